// Round 1
// baseline (6791.170 us; speedup 1.0000x reference)
//
#include <hip/hip_runtime.h>
#include <hip/hip_bf16.h>

#define T_ 512
#define B_ 256
#define I_ 256
#define H_ 512

#define NGROUP 16            // batch row-groups (16 rows each)
#define FLAG_BYTES (NGROUP * T_ * 4)

typedef _Float16 f16x8 __attribute__((ext_vector_type(8)));
typedef float f32x4 __attribute__((ext_vector_type(4)));

__device__ __forceinline__ float tanh_fast(float v) {
  // tanh(v) = 1 - 2/(exp(2v)+1); exact at +-inf, rel err ~1e-6
  float e = __expf(2.0f * v);
  return 1.0f - 2.0f / (e + 1.0f);
}

__device__ __forceinline__ f16x8 cvt8(const float4 a, const float4 b) {
  f16x8 f;
  f[0] = (_Float16)a.x; f[1] = (_Float16)a.y; f[2] = (_Float16)a.z; f[3] = (_Float16)a.w;
  f[4] = (_Float16)b.x; f[5] = (_Float16)b.y; f[6] = (_Float16)b.z; f[7] = (_Float16)b.w;
  return f;
}

// -------------------------------------------------------------------------
// Persistent fused recurrence: 64 blocks x 256 threads.
// block = (group g = bid>>2: rows g*16..+16) x (slice s = bid&3: cols s*128..+128)
// W_hh slice [512k x 128n] + W_ih slice [256k x 128n] live in VGPRs as f16
// MFMA B-fragments. h exchanged between the 4 blocks of a group through hs
// (global) with agent-scope release/acquire counters.
// -------------------------------------------------------------------------
__global__ __launch_bounds__(256, 1) void rnn_recurrence(
    const float* __restrict__ x,      // [T,B,I]
    const float* __restrict__ w_ih,   // [H,I]
    const float* __restrict__ w_hh,   // [H,H]
    const float* __restrict__ b_ih,   // [H]
    const float* __restrict__ b_hh,   // [H]
    int* __restrict__ flags,          // [NGROUP*T]
    _Float16* __restrict__ hs)        // [(T+1)*B, H]; hs[0]=0 pre-zeroed
{
  const int tid  = threadIdx.x;
  const int lane = tid & 63;
  const int w    = tid >> 6;        // wave 0..3
  const int bid  = blockIdx.x;
  const int g    = bid >> 2;        // row group 0..15
  const int s    = bid & 3;         // n-slice 0..3
  const int r0   = g * 16;
  const int c0   = s * 128;
  const int lrow = lane & 15;       // A-row index / D-col index
  const int quad = lane >> 4;
  const int kq   = quad * 8;

  __shared__ _Float16 hbuf[16][512 + 8];
  __shared__ _Float16 xbuf[16][256 + 8];

  // ---- preload weight fragments into registers (per wave: n-tiles 2w, 2w+1)
  f16x8 whh0[16], whh1[16];
  f16x8 wih0[8], wih1[8];
  const int n0c = c0 + (2 * w + 0) * 16 + lrow;
  const int n1c = c0 + (2 * w + 1) * 16 + lrow;
  const float bias0 = b_ih[n0c] + b_hh[n0c];
  const float bias1 = b_ih[n1c] + b_hh[n1c];
  #pragma unroll
  for (int kt = 0; kt < 16; ++kt) {
    const int k = kt * 32 + kq;
    whh0[kt] = cvt8(*(const float4*)(w_hh + (size_t)n0c * H_ + k),
                    *(const float4*)(w_hh + (size_t)n0c * H_ + k + 4));
    whh1[kt] = cvt8(*(const float4*)(w_hh + (size_t)n1c * H_ + k),
                    *(const float4*)(w_hh + (size_t)n1c * H_ + k + 4));
  }
  #pragma unroll
  for (int kt = 0; kt < 8; ++kt) {
    const int k = kt * 32 + kq;
    wih0[kt] = cvt8(*(const float4*)(w_ih + (size_t)n0c * I_ + k),
                    *(const float4*)(w_ih + (size_t)n0c * I_ + k + 4));
    wih1[kt] = cvt8(*(const float4*)(w_ih + (size_t)n1c * I_ + k),
                    *(const float4*)(w_ih + (size_t)n1c * I_ + k + 4));
  }

  for (int t = 0; t < T_; ++t) {
    // wait until all 4 blocks of the group finished writing hs[t]
    if (t > 0) {
      while (__hip_atomic_load(&flags[g * T_ + (t - 1)], __ATOMIC_ACQUIRE,
                               __HIP_MEMORY_SCOPE_AGENT) < 4) {
        __builtin_amdgcn_s_sleep(1);
      }
    }
    __syncthreads();   // also protects LDS from previous iteration's readers

    // ---- stage h_t (16 x 512 f16) into LDS
    {
      const _Float16* src = hs + ((size_t)t * B_ + r0) * H_;
      #pragma unroll
      for (int c = tid; c < 1024; c += 256) {
        const int row = c >> 6;
        const int col = (c & 63) * 8;
        *(uint4*)(&hbuf[row][col]) = *(const uint4*)(src + (size_t)row * H_ + col);
      }
    }
    // ---- stage x_t rows (16 x 256 fp32 -> f16) into LDS
    {
      const float* src = x + ((size_t)t * B_ + r0) * I_;
      #pragma unroll
      for (int c = tid; c < 512; c += 256) {
        const int row = c >> 5;
        const int col = (c & 31) * 8;
        *(f16x8*)(&xbuf[row][col]) =
            cvt8(*(const float4*)(src + (size_t)row * I_ + col),
                 *(const float4*)(src + (size_t)row * I_ + col + 4));
      }
    }
    __syncthreads();

    // ---- pre = h_t @ Whh_slice + x_t @ Wih_slice
    f32x4 acc0 = {0.f, 0.f, 0.f, 0.f};
    f32x4 acc1 = {0.f, 0.f, 0.f, 0.f};
    #pragma unroll
    for (int kt = 0; kt < 16; ++kt) {
      const f16x8 a = *(const f16x8*)(&hbuf[lrow][kt * 32 + kq]);
      acc0 = __builtin_amdgcn_mfma_f32_16x16x32_f16(a, whh0[kt], acc0, 0, 0, 0);
      acc1 = __builtin_amdgcn_mfma_f32_16x16x32_f16(a, whh1[kt], acc1, 0, 0, 0);
    }
    #pragma unroll
    for (int kt = 0; kt < 8; ++kt) {
      const f16x8 a = *(const f16x8*)(&xbuf[lrow][kt * 32 + kq]);
      acc0 = __builtin_amdgcn_mfma_f32_16x16x32_f16(a, wih0[kt], acc0, 0, 0, 0);
      acc1 = __builtin_amdgcn_mfma_f32_16x16x32_f16(a, wih1[kt], acc1, 0, 0, 0);
    }

    // ---- epilogue: tanh, store h_{t+1} slice (C/D: row=quad*4+r, col=lane&15)
    _Float16* dst = hs + (size_t)(t + 1) * B_ * H_;
    #pragma unroll
    for (int r = 0; r < 4; ++r) {
      const int row_g = r0 + quad * 4 + r;
      dst[(size_t)row_g * H_ + n0c] = (_Float16)tanh_fast(acc0[r] + bias0);
      dst[(size_t)row_g * H_ + n1c] = (_Float16)tanh_fast(acc1[r] + bias1);
    }
    __threadfence();       // agent-scope: publish h stores
    __syncthreads();       // all threads' stores+fences complete
    if (tid == 0) {
      __hip_atomic_fetch_add(&flags[g * T_ + t], 1, __ATOMIC_RELEASE,
                             __HIP_MEMORY_SCOPE_AGENT);
    }
  }
}

// -------------------------------------------------------------------------
// Output head: out[m,o] = hs[m+B,:] @ w_fc[o,:] + b_fc[o]
// M=T*B=131072, N=256, K=512. 64x64 block tile, 4 waves in 2x2.
// -------------------------------------------------------------------------
__global__ __launch_bounds__(256) void fc_head(
    const _Float16* __restrict__ hs,  // [(T+1)*B, H]
    const float* __restrict__ w_fc,   // [I, H]
    const float* __restrict__ b_fc,   // [I]
    float* __restrict__ out)          // [T*B, I]
{
  const int tid  = threadIdx.x;
  const int lane = tid & 63;
  const int w    = tid >> 6;
  const int wm   = w & 1;
  const int wn   = w >> 1;
  const int m0   = blockIdx.x * 64;
  const int n0   = blockIdx.y * 64;
  const int lrow = lane & 15;
  const int quad = lane >> 4;
  const int kq   = quad * 8;

  __shared__ _Float16 As[64][32 + 8];
  __shared__ _Float16 Bs[64][32 + 8];

  f32x4 acc00 = {0.f,0.f,0.f,0.f}, acc01 = {0.f,0.f,0.f,0.f};
  f32x4 acc10 = {0.f,0.f,0.f,0.f}, acc11 = {0.f,0.f,0.f,0.f};

  const int srow = tid >> 2;
  const int skc  = (tid & 3) * 8;

  for (int k0 = 0; k0 < H_; k0 += 32) {
    // A tile: hs rows m0..m0+63 (offset +B_ rows: hs[t+1]), f16 direct
    *(uint4*)(&As[srow][skc]) =
        *(const uint4*)(hs + (size_t)(B_ + m0 + srow) * H_ + k0 + skc);
    // B tile: w_fc rows n0..n0+63, fp32 -> f16
    *(f16x8*)(&Bs[srow][skc]) =
        cvt8(*(const float4*)(w_fc + (size_t)(n0 + srow) * H_ + k0 + skc),
             *(const float4*)(w_fc + (size_t)(n0 + srow) * H_ + k0 + skc + 4));
    __syncthreads();

    const f16x8 a0 = *(const f16x8*)(&As[wm * 32 + lrow][kq]);
    const f16x8 a1 = *(const f16x8*)(&As[wm * 32 + 16 + lrow][kq]);
    const f16x8 b0 = *(const f16x8*)(&Bs[wn * 32 + lrow][kq]);
    const f16x8 b1 = *(const f16x8*)(&Bs[wn * 32 + 16 + lrow][kq]);
    acc00 = __builtin_amdgcn_mfma_f32_16x16x32_f16(a0, b0, acc00, 0, 0, 0);
    acc01 = __builtin_amdgcn_mfma_f32_16x16x32_f16(a0, b1, acc01, 0, 0, 0);
    acc10 = __builtin_amdgcn_mfma_f32_16x16x32_f16(a1, b0, acc10, 0, 0, 0);
    acc11 = __builtin_amdgcn_mfma_f32_16x16x32_f16(a1, b1, acc11, 0, 0, 0);
    __syncthreads();
  }

  #pragma unroll
  for (int ni = 0; ni < 2; ++ni) {
    const int col = n0 + wn * 32 + ni * 16 + lrow;
    const float bf = b_fc[col];
    #pragma unroll
    for (int mi = 0; mi < 2; ++mi) {
      const f32x4 a = (mi == 0) ? (ni == 0 ? acc00 : acc01)
                                : (ni == 0 ? acc10 : acc11);
      #pragma unroll
      for (int r = 0; r < 4; ++r) {
        const int rowm = m0 + wm * 32 + mi * 16 + quad * 4 + r;
        out[(size_t)rowm * I_ + col] = a[r] + bf;
      }
    }
  }
}

extern "C" void kernel_launch(void* const* d_in, const int* in_sizes, int n_in,
                              void* d_out, int out_size, void* d_ws, size_t ws_size,
                              hipStream_t stream) {
  const float* x    = (const float*)d_in[0];
  const float* w_ih = (const float*)d_in[1];
  const float* w_hh = (const float*)d_in[2];
  const float* b_ih = (const float*)d_in[3];
  const float* b_hh = (const float*)d_in[4];
  const float* w_fc = (const float*)d_in[5];
  const float* b_fc = (const float*)d_in[6];
  float* out = (float*)d_out;

  int* flags    = (int*)d_ws;
  _Float16* hs  = (_Float16*)((char*)d_ws + FLAG_BYTES);

  // zero flags + hs[0] (h0 = 0); ws is re-poisoned 0xAA before every launch
  hipMemsetAsync(d_ws, 0, FLAG_BYTES + (size_t)B_ * H_ * sizeof(_Float16), stream);

  rnn_recurrence<<<64, 256, 0, stream>>>(x, w_ih, w_hh, b_ih, b_hh, flags, hs);
  fc_head<<<dim3(2048, 4), 256, 0, stream>>>(hs, w_fc, b_fc, out);
}

// Round 2
// 1999.345 us; speedup vs baseline: 3.3967x; 3.3967x over previous
//
#include <hip/hip_runtime.h>
#include <hip/hip_bf16.h>

#define T_ 512
#define B_ 256
#define I_ 256
#define H_ 512

#define NG 16   // batch row-groups of 16 rows
#define NS 4    // column slices of 128 cols

// exchange ring: [2 slots][NG][H_ cols][8 row-pairs] u64, self-tagged words
#define RING_WPG (H_ * 8)                            // words per (slot,group)
#define RING_BYTES (2ull * NG * RING_WPG * 8)        // 1 MiB

typedef _Float16 f16x8 __attribute__((ext_vector_type(8)));
typedef float f32x4 __attribute__((ext_vector_type(4)));

__device__ __forceinline__ float tanh_fast(float v) {
  float e = __expf(2.0f * v);
  return 1.0f - 2.0f / (e + 1.0f);
}

__device__ __forceinline__ f16x8 cvt8(const float4 a, const float4 b) {
  f16x8 f;
  f[0] = (_Float16)a.x; f[1] = (_Float16)a.y; f[2] = (_Float16)a.z; f[3] = (_Float16)a.w;
  f[4] = (_Float16)b.x; f[5] = (_Float16)b.y; f[6] = (_Float16)b.z; f[7] = (_Float16)b.w;
  return f;
}

__device__ __forceinline__ unsigned long long pack2h(_Float16 a, _Float16 b, unsigned tag) {
  unsigned ua = __builtin_bit_cast(unsigned short, a);
  unsigned ub = __builtin_bit_cast(unsigned short, b);
  return (unsigned long long)(ua | (ub << 16)) | ((unsigned long long)tag << 32);
}

// -------------------------------------------------------------------------
// Persistent fused recurrence: 64 blocks x 256 threads, 1 block/CU.
// group g = bid & 15 (rows g*16..+16); slice s = bid >> 4 (cols s*128..+128)
// -> the 4 blocks of a group are bids {g, g+16, g+32, g+48} (same XCD under
//    round-robin dispatch; perf heuristic only).
// W_hh / W_ih slices register-resident as f16 B-fragments. h exchanged via
// self-tagged u64 ring words with RELAXED agent atomics (no fences -> no
// per-step L2 writeback/invalidate). Own slice kept in LDS.
// -------------------------------------------------------------------------
__global__ __launch_bounds__(256, 1) void rnn_recurrence(
    const float* __restrict__ x,      // [T,B,I]
    const float* __restrict__ w_ih,   // [H,I]
    const float* __restrict__ w_hh,   // [H,H]
    const float* __restrict__ b_ih,   // [H]
    const float* __restrict__ b_hh,   // [H]
    unsigned long long* __restrict__ ring,
    _Float16* __restrict__ hs)        // [T,B,H]; hs[t] = h_{t+1}
{
  const int tid  = threadIdx.x;
  const int lane = tid & 63;
  const int w    = tid >> 6;        // wave 0..3
  const int bid  = blockIdx.x;
  const int g    = bid & 15;        // row group
  const int s    = bid >> 4;        // col slice
  const int r0   = g * 16;
  const int c0   = s * 128;
  const int lrow = lane & 15;
  const int quad = lane >> 4;
  const int kq   = quad * 8;

  __shared__ _Float16 hbuf[16][512 + 8];
  __shared__ _Float16 xbuf[16][256 + 8];

  // ---- weight fragments into registers (per wave: n-tiles 2w, 2w+1)
  f16x8 whh0[16], whh1[16];
  f16x8 wih0[8], wih1[8];
  const int n0c = c0 + (2 * w + 0) * 16 + lrow;   // global col of acc0
  const int n1c = c0 + (2 * w + 1) * 16 + lrow;   // global col of acc1
  const float bias0 = b_ih[n0c] + b_hh[n0c];
  const float bias1 = b_ih[n1c] + b_hh[n1c];
  #pragma unroll
  for (int kt = 0; kt < 16; ++kt) {
    const int k = kt * 32 + kq;
    whh0[kt] = cvt8(*(const float4*)(w_hh + (size_t)n0c * H_ + k),
                    *(const float4*)(w_hh + (size_t)n0c * H_ + k + 4));
    whh1[kt] = cvt8(*(const float4*)(w_hh + (size_t)n1c * H_ + k),
                    *(const float4*)(w_hh + (size_t)n1c * H_ + k + 4));
  }
  #pragma unroll
  for (int kt = 0; kt < 8; ++kt) {
    const int k = kt * 32 + kq;
    wih0[kt] = cvt8(*(const float4*)(w_ih + (size_t)n0c * I_ + k),
                    *(const float4*)(w_ih + (size_t)n0c * I_ + k + 4));
    wih1[kt] = cvt8(*(const float4*)(w_ih + (size_t)n1c * I_ + k),
                    *(const float4*)(w_ih + (size_t)n1c * I_ + k + 4));
  }

  // ---- per-thread remote-word map: 3 remote slices x 128 cols x 8 pairs = 3072 u64
  int colf[12], prow[12];
  int roff[12];
  #pragma unroll
  for (int j = 0; j < 12; ++j) {
    const int wdx = tid + j * 256;            // 0..3071
    const int rs  = wdx >> 10;                // remote slice idx 0..2
    const int sl  = rs + (rs >= s ? 1 : 0);   // actual slice (skip own)
    const int c   = (wdx >> 3) & 127;
    const int p   = wdx & 7;
    colf[j] = sl * 128 + c;
    prow[j] = p * 2;
    roff[j] = colf[j] * 8 + p;
  }

  // ---- init own LDS slice to h_0 = 0
  {
    const int row = tid >> 4, ch = tid & 15;          // 256 = 16 rows x 16 chunks
    f16x8 z = {0, 0, 0, 0, 0, 0, 0, 0};
    *(f16x8*)(&hbuf[row][c0 + ch * 8]) = z;
  }

  for (int t = 0; t < T_; ++t) {
    // ---- phase A: stage x_t (plain loads, overlaps poll) + poll remote h_t
    {
      const float* src = x + ((size_t)t * B_ + r0) * I_;
      #pragma unroll
      for (int c = tid; c < 512; c += 256) {
        const int row = c >> 5;
        const int col = (c & 31) * 8;
        *(f16x8*)(&xbuf[row][col]) =
            cvt8(*(const float4*)(src + (size_t)row * I_ + col),
                 *(const float4*)(src + (size_t)row * I_ + col + 4));
      }
    }
    {
      const unsigned long long* rg =
          ring + ((size_t)((t & 1) ? NG : 0) + g) * RING_WPG;
      unsigned long long v[12];
      #pragma unroll
      for (int j = 0; j < 12; ++j)
        v[j] = __hip_atomic_load(&rg[roff[j]], __ATOMIC_RELAXED,
                                 __HIP_MEMORY_SCOPE_AGENT);
      bool again = true;
      while (again) {
        again = false;
        #pragma unroll
        for (int j = 0; j < 12; ++j) {
          if ((unsigned)(v[j] >> 32) != (unsigned)t) {
            v[j] = __hip_atomic_load(&rg[roff[j]], __ATOMIC_RELAXED,
                                     __HIP_MEMORY_SCOPE_AGENT);
            again = true;
          }
        }
      }
      #pragma unroll
      for (int j = 0; j < 12; ++j) {
        const unsigned lo = (unsigned)v[j];
        hbuf[prow[j] + 0][colf[j]] =
            __builtin_bit_cast(_Float16, (unsigned short)(lo & 0xffff));
        hbuf[prow[j] + 1][colf[j]] =
            __builtin_bit_cast(_Float16, (unsigned short)(lo >> 16));
      }
    }
    __syncthreads();   // B: h_t + x_t staged

    // ---- phase C: write hs[t-1] = h_t own slice from LDS (coalesced)
    if (t > 0) {
      const int row = tid >> 4, ch = tid & 15;
      *(uint4*)(hs + ((size_t)(t - 1) * B_ + r0 + row) * H_ + c0 + ch * 8) =
          *(const uint4*)(&hbuf[row][c0 + ch * 8]);
    }

    // ---- MFMA: pre = h_t @ Whh_slice + x_t @ Wih_slice (4 indep 12-chains)
    f32x4 a0a = {0.f,0.f,0.f,0.f}, a0b = {0.f,0.f,0.f,0.f};
    f32x4 a1a = {0.f,0.f,0.f,0.f}, a1b = {0.f,0.f,0.f,0.f};
    #pragma unroll
    for (int kt = 0; kt < 8; ++kt) {
      const f16x8 a = *(const f16x8*)(&hbuf[lrow][kt * 32 + kq]);
      a0a = __builtin_amdgcn_mfma_f32_16x16x32_f16(a, whh0[kt], a0a, 0, 0, 0);
      a1a = __builtin_amdgcn_mfma_f32_16x16x32_f16(a, whh1[kt], a1a, 0, 0, 0);
    }
    #pragma unroll
    for (int kt = 8; kt < 16; ++kt) {
      const f16x8 a = *(const f16x8*)(&hbuf[lrow][kt * 32 + kq]);
      a0b = __builtin_amdgcn_mfma_f32_16x16x32_f16(a, whh0[kt], a0b, 0, 0, 0);
      a1b = __builtin_amdgcn_mfma_f32_16x16x32_f16(a, whh1[kt], a1b, 0, 0, 0);
    }
    #pragma unroll
    for (int kt = 0; kt < 4; ++kt) {
      const f16x8 a = *(const f16x8*)(&xbuf[lrow][kt * 32 + kq]);
      a0a = __builtin_amdgcn_mfma_f32_16x16x32_f16(a, wih0[kt], a0a, 0, 0, 0);
      a1a = __builtin_amdgcn_mfma_f32_16x16x32_f16(a, wih1[kt], a1a, 0, 0, 0);
    }
    #pragma unroll
    for (int kt = 4; kt < 8; ++kt) {
      const f16x8 a = *(const f16x8*)(&xbuf[lrow][kt * 32 + kq]);
      a0b = __builtin_amdgcn_mfma_f32_16x16x32_f16(a, wih0[kt], a0b, 0, 0, 0);
      a1b = __builtin_amdgcn_mfma_f32_16x16x32_f16(a, wih1[kt], a1b, 0, 0, 0);
    }
    const f32x4 acc0 = a0a + a0b;
    const f32x4 acc1 = a1a + a1b;

    __syncthreads();   // D: all LDS reads of h_t done before overwrite

    // ---- phase E: tanh, publish h_{t+1} (own LDS + tagged ring words)
    _Float16 e0[4], e1[4];
    #pragma unroll
    for (int r = 0; r < 4; ++r) {
      e0[r] = (_Float16)tanh_fast(acc0[r] + bias0);
      e1[r] = (_Float16)tanh_fast(acc1[r] + bias1);
      hbuf[quad * 4 + r][n0c] = e0[r];
      hbuf[quad * 4 + r][n1c] = e1[r];
    }
    {
      unsigned long long* rn =
          ring + ((size_t)(((t + 1) & 1) ? NG : 0) + g) * RING_WPG;
      const unsigned tag = (unsigned)(t + 1);
      __hip_atomic_store(&rn[n0c * 8 + quad * 2 + 0], pack2h(e0[0], e0[1], tag),
                         __ATOMIC_RELAXED, __HIP_MEMORY_SCOPE_AGENT);
      __hip_atomic_store(&rn[n0c * 8 + quad * 2 + 1], pack2h(e0[2], e0[3], tag),
                         __ATOMIC_RELAXED, __HIP_MEMORY_SCOPE_AGENT);
      __hip_atomic_store(&rn[n1c * 8 + quad * 2 + 0], pack2h(e1[0], e1[1], tag),
                         __ATOMIC_RELAXED, __HIP_MEMORY_SCOPE_AGENT);
      __hip_atomic_store(&rn[n1c * 8 + quad * 2 + 1], pack2h(e1[2], e1[3], tag),
                         __ATOMIC_RELAXED, __HIP_MEMORY_SCOPE_AGENT);
    }
  }

  // ---- final: hs[T-1] = h_T own slice
  __syncthreads();
  {
    const int row = tid >> 4, ch = tid & 15;
    *(uint4*)(hs + ((size_t)(T_ - 1) * B_ + r0 + row) * H_ + c0 + ch * 8) =
        *(const uint4*)(&hbuf[row][c0 + ch * 8]);
  }
}

// -------------------------------------------------------------------------
// Output head: out[m,o] = hs[m,:] @ w_fc[o,:] + b_fc[o]
// M=T*B=131072, N=256, K=512. 64x64 block tile, 4 waves in 2x2.
// -------------------------------------------------------------------------
__global__ __launch_bounds__(256) void fc_head(
    const _Float16* __restrict__ hs,  // [T*B, H]
    const float* __restrict__ w_fc,   // [I, H]
    const float* __restrict__ b_fc,   // [I]
    float* __restrict__ out)          // [T*B, I]
{
  const int tid  = threadIdx.x;
  const int lane = tid & 63;
  const int w    = tid >> 6;
  const int wm   = w & 1;
  const int wn   = w >> 1;
  const int m0   = blockIdx.x * 64;
  const int n0   = blockIdx.y * 64;
  const int lrow = lane & 15;
  const int quad = lane >> 4;
  const int kq   = quad * 8;

  __shared__ _Float16 As[64][32 + 8];
  __shared__ _Float16 Bs[64][32 + 8];

  f32x4 acc00 = {0.f,0.f,0.f,0.f}, acc01 = {0.f,0.f,0.f,0.f};
  f32x4 acc10 = {0.f,0.f,0.f,0.f}, acc11 = {0.f,0.f,0.f,0.f};

  const int srow = tid >> 2;
  const int skc  = (tid & 3) * 8;

  for (int k0 = 0; k0 < H_; k0 += 32) {
    *(uint4*)(&As[srow][skc]) =
        *(const uint4*)(hs + (size_t)(m0 + srow) * H_ + k0 + skc);
    *(f16x8*)(&Bs[srow][skc]) =
        cvt8(*(const float4*)(w_fc + (size_t)(n0 + srow) * H_ + k0 + skc),
             *(const float4*)(w_fc + (size_t)(n0 + srow) * H_ + k0 + skc + 4));
    __syncthreads();

    const f16x8 a0 = *(const f16x8*)(&As[wm * 32 + lrow][kq]);
    const f16x8 a1 = *(const f16x8*)(&As[wm * 32 + 16 + lrow][kq]);
    const f16x8 b0 = *(const f16x8*)(&Bs[wn * 32 + lrow][kq]);
    const f16x8 b1 = *(const f16x8*)(&Bs[wn * 32 + 16 + lrow][kq]);
    acc00 = __builtin_amdgcn_mfma_f32_16x16x32_f16(a0, b0, acc00, 0, 0, 0);
    acc01 = __builtin_amdgcn_mfma_f32_16x16x32_f16(a0, b1, acc01, 0, 0, 0);
    acc10 = __builtin_amdgcn_mfma_f32_16x16x32_f16(a1, b0, acc10, 0, 0, 0);
    acc11 = __builtin_amdgcn_mfma_f32_16x16x32_f16(a1, b1, acc11, 0, 0, 0);
    __syncthreads();
  }

  #pragma unroll
  for (int ni = 0; ni < 2; ++ni) {
    const int col = n0 + wn * 32 + ni * 16 + lrow;
    const float bf = b_fc[col];
    #pragma unroll
    for (int mi = 0; mi < 2; ++mi) {
      const f32x4 a = (mi == 0) ? (ni == 0 ? acc00 : acc01)
                                : (ni == 0 ? acc10 : acc11);
      #pragma unroll
      for (int r = 0; r < 4; ++r) {
        const int rowm = m0 + wm * 32 + mi * 16 + quad * 4 + r;
        out[(size_t)rowm * I_ + col] = a[r] + bf;
      }
    }
  }
}

extern "C" void kernel_launch(void* const* d_in, const int* in_sizes, int n_in,
                              void* d_out, int out_size, void* d_ws, size_t ws_size,
                              hipStream_t stream) {
  const float* x    = (const float*)d_in[0];
  const float* w_ih = (const float*)d_in[1];
  const float* w_hh = (const float*)d_in[2];
  const float* b_ih = (const float*)d_in[3];
  const float* b_hh = (const float*)d_in[4];
  const float* w_fc = (const float*)d_in[5];
  const float* b_fc = (const float*)d_in[6];
  float* out = (float*)d_out;

  unsigned long long* ring = (unsigned long long*)d_ws;
  _Float16* hs = (_Float16*)((char*)d_ws + RING_BYTES);

  // zero ring slot 0 -> (tag 0, h0 = 0) words; slot 1 poison tag never matches
  hipMemsetAsync(d_ws, 0, (size_t)NG * RING_WPG * 8, stream);

  rnn_recurrence<<<64, 256, 0, stream>>>(x, w_ih, w_hh, b_ih, b_hh, ring, hs);
  fc_head<<<dim3(2048, 4), 256, 0, stream>>>(hs, w_fc, b_fc, out);
}